// Round 1
// 593.798 us; speedup vs baseline: 1.0944x; 1.0944x over previous
//
#include <hip/hip_runtime.h>
#include <cstdint>
#include <cstddef>

// Problem shape (fixed by the reference): B=8, C=192, Tx=512, Ty=2048.
#define BB 8
#define CC 192
#define TXX 512
#define TYY 2048
#define NG_MAX (TYY / 8)   // 256 groups of 8 rows

#define NEG_INF (-1e9f)
#define HALF_LOG_2PI 0.9189385332046727f  // 0.5*log(2*pi)

// ---- output layout (floats, concatenated in return order) ----
#define O1 8388608
#define O2 11534336
#define O3 14680064
#define O4 14680065

// ---- workspace layout (bytes) ----
#define WS_NEG   0           // neg_cent fp32 [B,Ty,Tx]           33,554,432 B
#define WS_S     33554432    // s_p_sq_r [B,C,Tx]                  3,145,728 B
#define WS_MSR   36700160    // m_p * s  [B,C,Tx]                  3,145,728 B
#define WS_BIAS  39845888    // nc1+nc4  [B,Tx]                       16,384 B
#define WS_DIRS  39862272    // dir bits [B,Ty/4,64] dwords        1,048,576 B
#define WS_IDX   40910848    // idx_map  [B,Ty] int                   65,536 B
#define WS_LENS  40976384    // int text_len[8], spec_len[8]             64 B
#define WS_PART  40976448    // kl partials [3072] float              12,288 B

// ---------------------------------------------------------------------------
__global__ void k_zero(float* __restrict__ out) {
    int64_t i = (int64_t)blockIdx.x * blockDim.x + threadIdx.x;
    const int64_t n4 = (int64_t)BB * TYY * TXX / 4;
    float4 z4 = make_float4(0.f, 0.f, 0.f, 0.f);
    float4* p4 = (float4*)out;
    for (int64_t k = i; k < n4; k += (int64_t)gridDim.x * blockDim.x) p4[k] = z4;
    if (i < BB * TXX) out[O4 + i] = 0.0f;
}

__global__ void k_prep(const float* __restrict__ logs_p, const float* __restrict__ m_p,
                       float* __restrict__ s, float* __restrict__ msr) {
    int i = blockIdx.x * blockDim.x + threadIdx.x;
    float lp = logs_p[i], m = m_p[i];
    float sv = expf(-2.0f * lp);
    s[i] = sv;
    msr[i] = m * sv;
}

__global__ void k_bias(const float* __restrict__ logs_p, const float* __restrict__ m_p,
                       const float* __restrict__ msr, float* __restrict__ bias) {
    int i = blockIdx.x * blockDim.x + threadIdx.x;  // B*Tx = 4096 threads
    int b = i >> 9, x = i & (TXX - 1);
    size_t base = (size_t)b * CC * TXX + x;
    const float* lpb = logs_p + base;
    const float* mb  = m_p + base;
    const float* msb = msr + base;
    float acc = 0.f;
#pragma unroll 8
    for (int c = 0; c < CC; ++c)
        acc += -HALF_LOG_2PI - lpb[(size_t)c * TXX] - 0.5f * mb[(size_t)c * TXX] * msb[(size_t)c * TXX];
    bias[i] = acc;
}

__global__ void k_len(const float* __restrict__ tmask, const float* __restrict__ smask,
                      int* __restrict__ lens) {
    __shared__ float red[256];
    int b = blockIdx.x, tid = threadIdx.x;
    float ts = 0.f;
    for (int i = tid; i < TXX; i += 256) ts += tmask[b * TXX + i];
    red[tid] = ts; __syncthreads();
    for (int s = 128; s > 0; s >>= 1) { if (tid < s) red[tid] += red[tid + s]; __syncthreads(); }
    if (tid == 0) lens[b] = (int)(red[0] + 0.5f);
    __syncthreads();
    float ss = 0.f;
    for (int i = tid; i < TYY; i += 256) ss += smask[b * TYY + i];
    red[tid] = ss; __syncthreads();
    for (int s = 128; s > 0; s >>= 1) { if (tid < s) red[tid] += red[tid + s]; __syncthreads(); }
    if (tid == 0) lens[8 + b] = (int)(red[0] + 0.5f);
}

// neg_cent GEMM (R11 v1 tile: 64x64, BK=16, 8 blocks/CU).
// R14: blocks whose tile lies fully in the masked region (x0 >= text_len or
// t0 >= spec_len) exit before any work/barrier (condition is block-uniform).
// Safety: k_fwd only consumes rows y < 8*ceil(slen/8) (covered: their tiles
// have t0 < slen) and columns x >= tlen never influence x < tlen in the DP
// (left-to-right recurrence) nor the backtrack (idx starts at tlen-1).
// Poison floats there (0xAA.. = -3e-13, not NaN) are harmless.
__global__ __launch_bounds__(256) void k_gemm(const float* __restrict__ z,
                                              const float* __restrict__ msr,
                                              const float* __restrict__ sarr,
                                              const float* __restrict__ bias,
                                              const int* __restrict__ lens,
                                              float* __restrict__ neg) {
    int x0 = blockIdx.x * 64, t0 = blockIdx.y * 64, b = blockIdx.z;
    if (x0 >= lens[b] || t0 >= lens[8 + b]) return;   // masked tile

    __shared__ float Zs[16][68], Ms[16][68], Ss[16][68];  // +4 pad
    int tid = threadIdx.x;
    int tx = tid & 15, ty = tid >> 4;
    const float* zb = z    + (size_t)b * CC * TYY;
    const float* mb = msr  + (size_t)b * CC * TXX;
    const float* sb = sarr + (size_t)b * CC * TXX;
    int lr = tid >> 4, lc = (tid & 15) * 4;
    float acc[4][4] = {};
    for (int k0 = 0; k0 < CC; k0 += 16) {
        float4 zv = *(const float4*)(zb + (size_t)(k0 + lr) * TYY + t0 + lc);
        float4 mv = *(const float4*)(mb + (size_t)(k0 + lr) * TXX + x0 + lc);
        float4 sv = *(const float4*)(sb + (size_t)(k0 + lr) * TXX + x0 + lc);
        __syncthreads();
        *(float4*)&Zs[lr][lc] = zv;
        *(float4*)&Ms[lr][lc] = mv;
        *(float4*)&Ss[lr][lc] = sv;
        __syncthreads();
#pragma unroll
        for (int k = 0; k < 16; ++k) {
            float4 a4  = *(const float4*)&Zs[k][ty * 4];
            float4 bm4 = *(const float4*)&Ms[k][tx * 4];
            float4 bs4 = *(const float4*)&Ss[k][tx * 4];
            float av[4]  = {a4.x, a4.y, a4.z, a4.w};
            float bmv[4] = {bm4.x, bm4.y, bm4.z, bm4.w};
            float bsv[4] = {bs4.x, bs4.y, bs4.z, bs4.w};
#pragma unroll
            for (int i2 = 0; i2 < 4; ++i2) {
                float a2 = -0.5f * av[i2] * av[i2];
#pragma unroll
                for (int j = 0; j < 4; ++j)
                    acc[i2][j] += av[i2] * bmv[j] + a2 * bsv[j];
            }
        }
    }
    float4 b4 = *(const float4*)(bias + b * TXX + x0 + tx * 4);
    float bv[4] = {b4.x, b4.y, b4.z, b4.w};
#pragma unroll
    for (int i2 = 0; i2 < 4; ++i2) {
        int t = t0 + ty * 4 + i2;
        float4 o;
        o.x = acc[i2][0] + bv[0]; o.y = acc[i2][1] + bv[1];
        o.z = acc[i2][2] + bv[2]; o.w = acc[i2][3] + bv[3];
        *(float4*)(neg + ((size_t)b * TYY + t) * TXX + x0 + tx * 4) = o;
    }
}

// ---------------------------------------------------------------------------
// MAS forward pass v4 (R15): ONE wave per batch, zero LDS, zero barriers.
//
// Rationale (rocprof R14): k_fwd was 290 us with normalized VALUBusy ~21% on
// its 8 active CUs => ~80% stall. The stalls were structural: 256 six-wave
// lgkmcnt(0)+s_barrier phase round-trips, LDS-ring read latency with only a
// 2-row prefetch lead, and the A/B cross-wave boundary exchange. The only
// true serial dependency is the 2048-step y recurrence (~10 cyc/row chain).
//
// v4: 64 lanes x 8 cells/lane = 512 = Tx. Scores stream global->VGPR with a
// 3-buffer / 2-group (16-row) software prefetch (>1500 cycles of lead vs
// ~900-cycle HBM latency; compiler emits counted vmcnt waits — no barriers
// to force a drain). x-boundary: one wave_shr:1 DPP of v[7] per row.
// Direction bits are now fully lane-local: lane l owns byte l of each
// row-quad dword (x = 8l..8l+7), so the lane-pair dl-DPP disappears and the
// dirs layout is IDENTICAL to v3 (k_bwd unchanged).
// All buffers statically indexed (3-phase rotation) so they live in VGPRs.
// ---------------------------------------------------------------------------
#define LOADG(DST, G) do {                                        \
    const float4* gp_ = nc4 + (size_t)(G) * 1024 + 2 * lane;      \
    _Pragma("unroll")                                             \
    for (int r_ = 0; r_ < 8; ++r_) {                              \
        DST[2 * r_]     = gp_[r_ * 128];                          \
        DST[2 * r_ + 1] = gp_[r_ * 128 + 1];                      \
    }                                                             \
} while (0)

#define DPROW(CUR, YB, R) do {                                                \
    int y_ = (YB) + (R);                                                      \
    float s0_ = CUR[2*(R)].x,   s1_ = CUR[2*(R)].y;                           \
    float s2_ = CUR[2*(R)].z,   s3_ = CUR[2*(R)].w;                           \
    float s4_ = CUR[2*(R)+1].x, s5_ = CUR[2*(R)+1].y;                         \
    float s6_ = CUR[2*(R)+1].z, s7_ = CUR[2*(R)+1].w;                         \
    unsigned d_ = 0;                                                          \
    if (y_ == 0) {                                                            \
        if (lane == 0) v[0] = s0_;   /* only x==0 scored on row 0 */          \
    } else {                                                                  \
        float pl_ = __int_as_float(__builtin_amdgcn_update_dpp(               \
            0, __float_as_int(v[7]), 0x138, 0xF, 0xF, false));                \
        if (lane == 0) pl_ = NEG_INF;                                         \
        float n0_ = s0_ + fmaxf(v[0], pl_);  if (pl_  > v[0]) d_ |= 1u;       \
        float n1_ = s1_ + fmaxf(v[1], v[0]); if (v[0] > v[1]) d_ |= 2u;       \
        float n2_ = s2_ + fmaxf(v[2], v[1]); if (v[1] > v[2]) d_ |= 4u;       \
        float n3_ = s3_ + fmaxf(v[3], v[2]); if (v[2] > v[3]) d_ |= 8u;       \
        float n4_ = s4_ + fmaxf(v[4], v[3]); if (v[3] > v[4]) d_ |= 16u;      \
        float n5_ = s5_ + fmaxf(v[5], v[4]); if (v[4] > v[5]) d_ |= 32u;      \
        float n6_ = s6_ + fmaxf(v[6], v[5]); if (v[5] > v[6]) d_ |= 64u;      \
        float n7_ = s7_ + fmaxf(v[7], v[6]); if (v[6] > v[7]) d_ |= 128u;     \
        v[0] = n0_; v[1] = n1_; v[2] = n2_; v[3] = n3_;                       \
        v[4] = n4_; v[5] = n5_; v[6] = n6_; v[7] = n7_;                       \
    }                                                                         \
    unsigned t_ = (unsigned)(y_ - 8 * lane);                                  \
    if (t_ < 8u) d_ |= 1u << t_;          /* fold x==y for backtrack */       \
    acc |= d_ << (((R) & 3) * 8);                                             \
    if (((R) & 3) == 3) { db32[(y_ >> 2) * 64 + lane] = acc; acc = 0; }       \
} while (0)

#define FWD_ITER(G, CUR, NXT) do {                                \
    int g_ = (G);                                                 \
    if (g_ + 2 < ng) LOADG(NXT, g_ + 2);  /* prefetch 2 ahead */  \
    int yb_ = 8 * g_;                                             \
    DPROW(CUR, yb_, 0); DPROW(CUR, yb_, 1);                       \
    DPROW(CUR, yb_, 2); DPROW(CUR, yb_, 3);                       \
    DPROW(CUR, yb_, 4); DPROW(CUR, yb_, 5);                       \
    DPROW(CUR, yb_, 6); DPROW(CUR, yb_, 7);                       \
} while (0)

__global__ __launch_bounds__(64, 1) void k_fwd(const float* __restrict__ neg,
                                               const int* __restrict__ lens,
                                               uint32_t* __restrict__ dirs) {
    int b = blockIdx.x, lane = threadIdx.x;
    const float4* nc4 = (const float4*)(neg + (size_t)b * TYY * TXX);
    uint32_t* db32 = dirs + (size_t)b * (TYY / 4) * 64;
    int slen = lens[8 + b];
    int ng = (slen + 7) >> 3;    // 192..256 (slen >= 1536)

    float v[8];
#pragma unroll
    for (int j = 0; j < 8; ++j) v[j] = NEG_INF;
    unsigned acc = 0;

    float4 bufA[16], bufB[16], bufC[16];  // 3 groups in flight (static idx)
    LOADG(bufA, 0);
    LOADG(bufB, 1);

    for (int p = 0; p < ng; p += 3) {
        FWD_ITER(p, bufA, bufC);
        if (p + 1 < ng) FWD_ITER(p + 1, bufB, bufA);
        if (p + 2 < ng) FWD_ITER(p + 2, bufC, bufB);
    }
}

// MAS backtrack: 32-row slabs; lane j holds a 64-bit window of row y0-j's
// bits; move = (idx!=0) & bit (x==y folded in fwd).
__global__ __launch_bounds__(64, 1) void k_bwd(const int* __restrict__ lens,
                                               const uint32_t* __restrict__ dirs,
                                               int* __restrict__ idx_map) {
    int b = blockIdx.x, lane = threadIdx.x;
    const uint32_t* db32 = dirs + (size_t)b * (TYY / 4) * 64;
    int tlen = lens[b], slen = lens[8 + b];

    int idx = tlen - 1;
    int y0 = slen - 1;
    while (y0 >= 0) {
        int nsteps = (y0 + 1 < 32) ? y0 + 1 : 32;
        int y = y0 - lane;
        int yy = (y < 0) ? 0 : y;
        int w0 = (idx >> 5) - 1;
        if (w0 < 0) w0 = 0;
        if (w0 > 14) w0 = 14;
        int qrow = (yy >> 2) * 64;
        int byteoff = (yy & 3) * 8;
        uint32_t lo = 0, hi = 0;
        if (lane < 32) {
#pragma unroll
            for (int k = 0; k < 4; ++k)
                lo |= ((db32[qrow + 4 * w0 + k] >> byteoff) & 0xffu) << (8 * k);
#pragma unroll
            for (int k = 0; k < 4; ++k)
                hi |= ((db32[qrow + 4 * w0 + 4 + k] >> byteoff) & 0xffu) << (8 * k);
        }
        int base = w0 << 5;
        int cap = 0;
#pragma unroll
        for (int j = 0; j < 32; ++j) {
            if (lane == j) cap = idx;
            uint32_t l = (uint32_t)__builtin_amdgcn_readlane((int)lo, j);
            uint32_t h = (uint32_t)__builtin_amdgcn_readlane((int)hi, j);
            int bp = idx - base;              // 0..63
            uint32_t word = (bp & 32) ? h : l;
            int bit = (int)((word >> (bp & 31)) & 1u);
            int move = (int)(idx != 0) & bit;
            idx -= move;
        }
        if (lane < nsteps) idx_map[b * TYY + (y0 - lane)] = cap;
        y0 -= 32;
    }
}

// Scatter path one-hots + duration histogram from idx_map.
__global__ void k_scatter(const int* __restrict__ lens, const int* __restrict__ idx_map,
                          float* __restrict__ out) {
    int i = blockIdx.x * blockDim.x + threadIdx.x;  // B*Ty threads
    int b = i >> 11, y = i & (TYY - 1);
    if (y < lens[8 + b]) {
        int x = idx_map[i];
        out[(size_t)i * TXX + x] = 1.0f;
        atomicAdd(&out[O4 + b * TXX + x], 1.0f);
    }
}

// Gather m_p/logs_p onto spec frames via idx_map; fused KL partial sums.
__global__ __launch_bounds__(256) void k_gather(const float* __restrict__ z_p,
                                                const float* __restrict__ m_p,
                                                const float* __restrict__ logs_p,
                                                const float* __restrict__ logs_q,
                                                const int* __restrict__ lens,
                                                const int* __restrict__ idx_map,
                                                float* __restrict__ out,
                                                float* __restrict__ partials) {
    const int S = BB * CC * TYY / 4;
    int base = blockIdx.x * 256 + threadIdx.x;
    float klsum = 0.f;
#pragma unroll
    for (int r = 0; r < 4; ++r) {
        int i = base + r * S;
        int t = i & (TYY - 1);
        int bc = i >> 11;
        int b = bc / CC;
        float ma = 0.f, la = 0.f;
        if (t < lens[8 + b]) {
            int x = idx_map[b * TYY + t];
            size_t off = (size_t)bc * TXX + x;
            ma = m_p[off];
            la = logs_p[off];
            float zv = z_p[i], lq = logs_q[i];
            float dz = zv - ma;
            klsum += la - lq - 0.5f + 0.5f * dz * dz * expf(-2.0f * la);
        }
        out[O1 + i] = ma;
        out[O2 + i] = la;
    }
    for (int o = 32; o > 0; o >>= 1) klsum += __shfl_down(klsum, o);
    __shared__ float red[4];
    if ((threadIdx.x & 63) == 0) red[threadIdx.x >> 6] = klsum;
    __syncthreads();
    if (threadIdx.x == 0) partials[blockIdx.x] = red[0] + red[1] + red[2] + red[3];
}

__global__ void k_final(const float* __restrict__ partials, const int* __restrict__ lens,
                        float* __restrict__ out) {
    float s = 0.f;
    for (int i = threadIdx.x; i < 3072; i += 256) s += partials[i];
    for (int o = 32; o > 0; o >>= 1) s += __shfl_down(s, o);
    __shared__ float red[4];
    if ((threadIdx.x & 63) == 0) red[threadIdx.x >> 6] = s;
    __syncthreads();
    if (threadIdx.x == 0) {
        float tot = 0.f;
        for (int b = 0; b < 8; ++b) tot += (float)lens[8 + b];
        out[O3] = (red[0] + red[1] + red[2] + red[3]) / tot;
    }
}

extern "C" void kernel_launch(void* const* d_in, const int* in_sizes, int n_in,
                              void* d_out, int out_size, void* d_ws, size_t ws_size,
                              hipStream_t stream) {
    const float* z_p    = (const float*)d_in[0];
    const float* m_p    = (const float*)d_in[1];
    const float* logs_p = (const float*)d_in[2];
    const float* logs_q = (const float*)d_in[3];
    const float* tmask  = (const float*)d_in[4];
    const float* smask  = (const float*)d_in[5];
    float* out = (float*)d_out;
    char* ws = (char*)d_ws;

    float*    neg      = (float*)(ws + WS_NEG);
    float*    sarr     = (float*)(ws + WS_S);
    float*    msr      = (float*)(ws + WS_MSR);
    float*    bias     = (float*)(ws + WS_BIAS);
    uint32_t* dirs     = (uint32_t*)(ws + WS_DIRS);
    int*      idx_map  = (int*)(ws + WS_IDX);
    int*      lens     = (int*)(ws + WS_LENS);
    float*    partials = (float*)(ws + WS_PART);

    hipLaunchKernelGGL(k_zero,    dim3(2048),      dim3(256), 0, stream, out);
    hipLaunchKernelGGL(k_prep,    dim3(3072),      dim3(256), 0, stream, logs_p, m_p, sarr, msr);
    hipLaunchKernelGGL(k_bias,    dim3(16),        dim3(256), 0, stream, logs_p, m_p, msr, bias);
    hipLaunchKernelGGL(k_len,     dim3(8),         dim3(256), 0, stream, tmask, smask, lens);
    hipLaunchKernelGGL(k_gemm,    dim3(8, 32, 8),  dim3(256), 0, stream, z_p, msr, sarr, bias, lens, neg);
    hipLaunchKernelGGL(k_fwd,     dim3(8),         dim3(64),  0, stream, neg, lens, dirs);
    hipLaunchKernelGGL(k_bwd,     dim3(8),         dim3(64),  0, stream, lens, dirs, idx_map);
    hipLaunchKernelGGL(k_scatter, dim3(64),        dim3(256), 0, stream, lens, idx_map, out);
    hipLaunchKernelGGL(k_gather,  dim3(3072),      dim3(256), 0, stream, z_p, m_p, logs_p, logs_q,
                       lens, idx_map, out, partials);
    hipLaunchKernelGGL(k_final,   dim3(1),         dim3(256), 0, stream, partials, lens, out);
}

// Round 2
// 564.144 us; speedup vs baseline: 1.1519x; 1.0526x over previous
//
#include <hip/hip_runtime.h>
#include <cstdint>
#include <cstddef>

// Problem shape (fixed by the reference): B=8, C=192, Tx=512, Ty=2048.
#define BB 8
#define CC 192
#define TXX 512
#define TYY 2048
#define NG_MAX (TYY / 8)   // 256 groups of 8 rows

#define NEG_INF (-1e9f)
#define HALF_LOG_2PI 0.9189385332046727f  // 0.5*log(2*pi)

// ---- output layout (floats, concatenated in return order) ----
#define O1 8388608
#define O2 11534336
#define O3 14680064
#define O4 14680065

// ---- workspace layout (bytes) ----
#define WS_NEG   0           // neg_cent fp32 [B,Ty,Tx]           33,554,432 B
#define WS_S     33554432    // s_p_sq_r [B,C,Tx]                  3,145,728 B
#define WS_MSR   36700160    // m_p * s  [B,C,Tx]                  3,145,728 B
#define WS_BIAS  39845888    // nc1+nc4  [B,Tx]                       16,384 B
#define WS_DIRS  39862272    // dir bits [B,Ty/4,64] dwords        1,048,576 B
#define WS_IDX   40910848    // idx_map  [B,Ty] int                   65,536 B
#define WS_LENS  40976384    // int text_len[8], spec_len[8]             64 B
#define WS_PART  40976448    // kl partials [3072] float              12,288 B

typedef float f32x4 __attribute__((ext_vector_type(4)));

// ---------------------------------------------------------------------------
__global__ void k_zero(float* __restrict__ out) {
    int64_t i = (int64_t)blockIdx.x * blockDim.x + threadIdx.x;
    const int64_t n4 = (int64_t)BB * TYY * TXX / 4;
    float4 z4 = make_float4(0.f, 0.f, 0.f, 0.f);
    float4* p4 = (float4*)out;
    for (int64_t k = i; k < n4; k += (int64_t)gridDim.x * blockDim.x) p4[k] = z4;
    if (i < BB * TXX) out[O4 + i] = 0.0f;
}

__global__ void k_prep(const float* __restrict__ logs_p, const float* __restrict__ m_p,
                       float* __restrict__ s, float* __restrict__ msr) {
    int i = blockIdx.x * blockDim.x + threadIdx.x;
    float lp = logs_p[i], m = m_p[i];
    float sv = expf(-2.0f * lp);
    s[i] = sv;
    msr[i] = m * sv;
}

__global__ void k_bias(const float* __restrict__ logs_p, const float* __restrict__ m_p,
                       const float* __restrict__ msr, float* __restrict__ bias) {
    int i = blockIdx.x * blockDim.x + threadIdx.x;  // B*Tx = 4096 threads
    int b = i >> 9, x = i & (TXX - 1);
    size_t base = (size_t)b * CC * TXX + x;
    const float* lpb = logs_p + base;
    const float* mb  = m_p + base;
    const float* msb = msr + base;
    float acc = 0.f;
#pragma unroll 8
    for (int c = 0; c < CC; ++c)
        acc += -HALF_LOG_2PI - lpb[(size_t)c * TXX] - 0.5f * mb[(size_t)c * TXX] * msb[(size_t)c * TXX];
    bias[i] = acc;
}

__global__ void k_len(const float* __restrict__ tmask, const float* __restrict__ smask,
                      int* __restrict__ lens) {
    __shared__ float red[256];
    int b = blockIdx.x, tid = threadIdx.x;
    float ts = 0.f;
    for (int i = tid; i < TXX; i += 256) ts += tmask[b * TXX + i];
    red[tid] = ts; __syncthreads();
    for (int s = 128; s > 0; s >>= 1) { if (tid < s) red[tid] += red[tid + s]; __syncthreads(); }
    if (tid == 0) lens[b] = (int)(red[0] + 0.5f);
    __syncthreads();
    float ss = 0.f;
    for (int i = tid; i < TYY; i += 256) ss += smask[b * TYY + i];
    red[tid] = ss; __syncthreads();
    for (int s = 128; s > 0; s >>= 1) { if (tid < s) red[tid] += red[tid + s]; __syncthreads(); }
    if (tid == 0) lens[8 + b] = (int)(red[0] + 0.5f);
}

// neg_cent GEMM (R11 v1 tile: 64x64, BK=16, 8 blocks/CU).
// R14: blocks whose tile lies fully in the masked region (x0 >= text_len or
// t0 >= spec_len) exit before any work/barrier (condition is block-uniform).
// Safety: k_fwd only consumes rows y < 8*ceil(slen/8) (covered: their tiles
// have t0 < slen) and columns x >= tlen never influence x < tlen in the DP
// (left-to-right recurrence) nor the backtrack (idx starts at tlen-1).
// Poison floats there (0xAA.. = -3e-13, not NaN) are harmless.
__global__ __launch_bounds__(256) void k_gemm(const float* __restrict__ z,
                                              const float* __restrict__ msr,
                                              const float* __restrict__ sarr,
                                              const float* __restrict__ bias,
                                              const int* __restrict__ lens,
                                              float* __restrict__ neg) {
    int x0 = blockIdx.x * 64, t0 = blockIdx.y * 64, b = blockIdx.z;
    if (x0 >= lens[b] || t0 >= lens[8 + b]) return;   // masked tile

    __shared__ float Zs[16][68], Ms[16][68], Ss[16][68];  // +4 pad
    int tid = threadIdx.x;
    int tx = tid & 15, ty = tid >> 4;
    const float* zb = z    + (size_t)b * CC * TYY;
    const float* mb = msr  + (size_t)b * CC * TXX;
    const float* sb = sarr + (size_t)b * CC * TXX;
    int lr = tid >> 4, lc = (tid & 15) * 4;
    float acc[4][4] = {};
    for (int k0 = 0; k0 < CC; k0 += 16) {
        float4 zv = *(const float4*)(zb + (size_t)(k0 + lr) * TYY + t0 + lc);
        float4 mv = *(const float4*)(mb + (size_t)(k0 + lr) * TXX + x0 + lc);
        float4 sv = *(const float4*)(sb + (size_t)(k0 + lr) * TXX + x0 + lc);
        __syncthreads();
        *(float4*)&Zs[lr][lc] = zv;
        *(float4*)&Ms[lr][lc] = mv;
        *(float4*)&Ss[lr][lc] = sv;
        __syncthreads();
#pragma unroll
        for (int k = 0; k < 16; ++k) {
            float4 a4  = *(const float4*)&Zs[k][ty * 4];
            float4 bm4 = *(const float4*)&Ms[k][tx * 4];
            float4 bs4 = *(const float4*)&Ss[k][tx * 4];
            float av[4]  = {a4.x, a4.y, a4.z, a4.w};
            float bmv[4] = {bm4.x, bm4.y, bm4.z, bm4.w};
            float bsv[4] = {bs4.x, bs4.y, bs4.z, bs4.w};
#pragma unroll
            for (int i2 = 0; i2 < 4; ++i2) {
                float a2 = -0.5f * av[i2] * av[i2];
#pragma unroll
                for (int j = 0; j < 4; ++j)
                    acc[i2][j] += av[i2] * bmv[j] + a2 * bsv[j];
            }
        }
    }
    float4 b4 = *(const float4*)(bias + b * TXX + x0 + tx * 4);
    float bv[4] = {b4.x, b4.y, b4.z, b4.w};
#pragma unroll
    for (int i2 = 0; i2 < 4; ++i2) {
        int t = t0 + ty * 4 + i2;
        float4 o;
        o.x = acc[i2][0] + bv[0]; o.y = acc[i2][1] + bv[1];
        o.z = acc[i2][2] + bv[2]; o.w = acc[i2][3] + bv[3];
        *(float4*)(neg + ((size_t)b * TYY + t) * TXX + x0 + tx * 4) = o;
    }
}

// ---------------------------------------------------------------------------
// MAS forward pass v5 (R16): one wave per batch, asm-pinned prefetch.
//
// R15 post-mortem: v4's C-level 3-buffer prefetch was DEFEATED by regalloc —
// VGPR_Count=116 < the 192 needed for 3 resident buffers, i.e. the compiler
// sank the loads to their uses, collapsing the 2-group lead. k_fwd stalled
// ~85% on global-load latency (normalized VALUBusy ~14%, 0 LDS conflicts).
//
// v5 pins the schedule: loads are asm volatile global_load_dwordx4 (with
// "memory" clobbers -> program order among loads/stores is fixed), and each
// group's consumption is gated by a counted s_waitcnt vmcnt(N) followed by
// sched_barrier(0) (rule #18: else the compiler hoists the register-only
// consumers above the waitcnt). vmcnt math, 16 loads/group + 2 dir-stores/
// group issued strictly between LOADG blocks:
//   steady state (prefetch g+2 issued): newest-in-flight = 16(g+2) + 2(st)
//     + 16(g+1) = 34 -> vmcnt(32) guarantees group g complete.
//   tail, no g+2 prefetch: vmcnt(16); last group: vmcnt(0).
// No barriers, no LDS. Dirs layout identical to v4 (k_bwd unchanged).
// ---------------------------------------------------------------------------
#define GLOAD4(DST, PTR, OFF)                                             \
    asm volatile("global_load_dwordx4 %0, %1, off offset:" #OFF           \
                 : "=v"(DST) : "v"(PTR) : "memory")

#define WAIT_VM(N) do {                                                   \
    asm volatile("s_waitcnt vmcnt(" #N ")" ::: "memory");                 \
    __builtin_amdgcn_sched_barrier(0);                                    \
} while (0)

// 8 rows x 512 floats; lane owns 32B (two float4) per row. 4 base pointers
// (rows {0,1},{2,3},{4,5},{6,7}), imm offsets {0,16,2048,2064} (13b signed).
#define LOADG(DST, G) do {                                                \
    const char* p0_ = (const char*)nc4 + (size_t)(G) * 16384 + lane * 32; \
    const char* p2_ = p0_ + 4096;                                         \
    const char* p4_ = p0_ + 8192;                                         \
    const char* p6_ = p0_ + 12288;                                        \
    GLOAD4(DST[0],  p0_, 0);    GLOAD4(DST[1],  p0_, 16);                 \
    GLOAD4(DST[2],  p0_, 2048); GLOAD4(DST[3],  p0_, 2064);               \
    GLOAD4(DST[4],  p2_, 0);    GLOAD4(DST[5],  p2_, 16);                 \
    GLOAD4(DST[6],  p2_, 2048); GLOAD4(DST[7],  p2_, 2064);               \
    GLOAD4(DST[8],  p4_, 0);    GLOAD4(DST[9],  p4_, 16);                 \
    GLOAD4(DST[10], p4_, 2048); GLOAD4(DST[11], p4_, 2064);               \
    GLOAD4(DST[12], p6_, 0);    GLOAD4(DST[13], p6_, 16);                 \
    GLOAD4(DST[14], p6_, 2048); GLOAD4(DST[15], p6_, 2064);               \
} while (0)

#define DPROW(CUR, YB, R) do {                                                \
    int y_ = (YB) + (R);                                                      \
    float s0_ = CUR[2*(R)][0],   s1_ = CUR[2*(R)][1];                         \
    float s2_ = CUR[2*(R)][2],   s3_ = CUR[2*(R)][3];                         \
    float s4_ = CUR[2*(R)+1][0], s5_ = CUR[2*(R)+1][1];                       \
    float s6_ = CUR[2*(R)+1][2], s7_ = CUR[2*(R)+1][3];                       \
    unsigned d_ = 0;                                                          \
    if (y_ == 0) {                                                            \
        if (lane == 0) v[0] = s0_;   /* only x==0 scored on row 0 */          \
    } else {                                                                  \
        float pl_ = __int_as_float(__builtin_amdgcn_update_dpp(               \
            0, __float_as_int(v[7]), 0x138, 0xF, 0xF, false));                \
        if (lane == 0) pl_ = NEG_INF;                                         \
        float n0_ = s0_ + fmaxf(v[0], pl_);  if (pl_  > v[0]) d_ |= 1u;       \
        float n1_ = s1_ + fmaxf(v[1], v[0]); if (v[0] > v[1]) d_ |= 2u;       \
        float n2_ = s2_ + fmaxf(v[2], v[1]); if (v[1] > v[2]) d_ |= 4u;       \
        float n3_ = s3_ + fmaxf(v[3], v[2]); if (v[2] > v[3]) d_ |= 8u;       \
        float n4_ = s4_ + fmaxf(v[4], v[3]); if (v[3] > v[4]) d_ |= 16u;      \
        float n5_ = s5_ + fmaxf(v[5], v[4]); if (v[4] > v[5]) d_ |= 32u;      \
        float n6_ = s6_ + fmaxf(v[6], v[5]); if (v[5] > v[6]) d_ |= 64u;      \
        float n7_ = s7_ + fmaxf(v[7], v[6]); if (v[6] > v[7]) d_ |= 128u;     \
        v[0] = n0_; v[1] = n1_; v[2] = n2_; v[3] = n3_;                       \
        v[4] = n4_; v[5] = n5_; v[6] = n6_; v[7] = n7_;                       \
    }                                                                         \
    unsigned t_ = (unsigned)(y_ - 8 * lane);                                  \
    if (t_ < 8u) d_ |= 1u << t_;          /* fold x==y for backtrack */       \
    acc |= d_ << (((R) & 3) * 8);                                             \
    if (((R) & 3) == 3) { db32[(y_ >> 2) * 64 + lane] = acc; acc = 0; }       \
} while (0)

#define FWD_ITER(G, CUR, NXT) do {                                \
    int g_ = (G);                                                 \
    if (g_ + 2 < ng) {                                            \
        LOADG(NXT, g_ + 2);  /* prefetch 2 ahead */               \
        WAIT_VM(32);                                              \
    } else if (g_ + 1 < ng) {                                     \
        WAIT_VM(16);                                              \
    } else {                                                      \
        WAIT_VM(0);                                               \
    }                                                             \
    int yb_ = 8 * g_;                                             \
    DPROW(CUR, yb_, 0); DPROW(CUR, yb_, 1);                       \
    DPROW(CUR, yb_, 2); DPROW(CUR, yb_, 3);                       \
    DPROW(CUR, yb_, 4); DPROW(CUR, yb_, 5);                       \
    DPROW(CUR, yb_, 6); DPROW(CUR, yb_, 7);                       \
} while (0)

__global__ __launch_bounds__(64, 1) void k_fwd(const float* __restrict__ neg,
                                               const int* __restrict__ lens,
                                               uint32_t* __restrict__ dirs) {
    int b = blockIdx.x, lane = threadIdx.x;
    const float* nc4 = neg + (size_t)b * TYY * TXX;   // byte math in LOADG
    uint32_t* db32 = dirs + (size_t)b * (TYY / 4) * 64;
    int slen = lens[8 + b];
    int ng = (slen + 7) >> 3;    // 192..256 (slen >= 1536)

    float v[8];
#pragma unroll
    for (int j = 0; j < 8; ++j) v[j] = NEG_INF;
    unsigned acc = 0;

    f32x4 bufA[16], bufB[16], bufC[16];  // 3 groups in flight, asm-pinned
    LOADG(bufA, 0);
    LOADG(bufB, 1);

    for (int p = 0; p < ng; p += 3) {
        FWD_ITER(p, bufA, bufC);
        if (p + 1 < ng) FWD_ITER(p + 1, bufB, bufA);
        if (p + 2 < ng) FWD_ITER(p + 2, bufC, bufB);
    }
}

// MAS backtrack: 32-row slabs; lane j holds a 64-bit window of row y0-j's
// bits; move = (idx!=0) & bit (x==y folded in fwd).
__global__ __launch_bounds__(64, 1) void k_bwd(const int* __restrict__ lens,
                                               const uint32_t* __restrict__ dirs,
                                               int* __restrict__ idx_map) {
    int b = blockIdx.x, lane = threadIdx.x;
    const uint32_t* db32 = dirs + (size_t)b * (TYY / 4) * 64;
    int tlen = lens[b], slen = lens[8 + b];

    int idx = tlen - 1;
    int y0 = slen - 1;
    while (y0 >= 0) {
        int nsteps = (y0 + 1 < 32) ? y0 + 1 : 32;
        int y = y0 - lane;
        int yy = (y < 0) ? 0 : y;
        int w0 = (idx >> 5) - 1;
        if (w0 < 0) w0 = 0;
        if (w0 > 14) w0 = 14;
        int qrow = (yy >> 2) * 64;
        int byteoff = (yy & 3) * 8;
        uint32_t lo = 0, hi = 0;
        if (lane < 32) {
#pragma unroll
            for (int k = 0; k < 4; ++k)
                lo |= ((db32[qrow + 4 * w0 + k] >> byteoff) & 0xffu) << (8 * k);
#pragma unroll
            for (int k = 0; k < 4; ++k)
                hi |= ((db32[qrow + 4 * w0 + 4 + k] >> byteoff) & 0xffu) << (8 * k);
        }
        int base = w0 << 5;
        int cap = 0;
#pragma unroll
        for (int j = 0; j < 32; ++j) {
            if (lane == j) cap = idx;
            uint32_t l = (uint32_t)__builtin_amdgcn_readlane((int)lo, j);
            uint32_t h = (uint32_t)__builtin_amdgcn_readlane((int)hi, j);
            int bp = idx - base;              // 0..63
            uint32_t word = (bp & 32) ? h : l;
            int bit = (int)((word >> (bp & 31)) & 1u);
            int move = (int)(idx != 0) & bit;
            idx -= move;
        }
        if (lane < nsteps) idx_map[b * TYY + (y0 - lane)] = cap;
        y0 -= 32;
    }
}

// Scatter path one-hots + duration histogram from idx_map.
__global__ void k_scatter(const int* __restrict__ lens, const int* __restrict__ idx_map,
                          float* __restrict__ out) {
    int i = blockIdx.x * blockDim.x + threadIdx.x;  // B*Ty threads
    int b = i >> 11, y = i & (TYY - 1);
    if (y < lens[8 + b]) {
        int x = idx_map[i];
        out[(size_t)i * TXX + x] = 1.0f;
        atomicAdd(&out[O4 + b * TXX + x], 1.0f);
    }
}

// Gather m_p/logs_p onto spec frames via idx_map; fused KL partial sums.
__global__ __launch_bounds__(256) void k_gather(const float* __restrict__ z_p,
                                                const float* __restrict__ m_p,
                                                const float* __restrict__ logs_p,
                                                const float* __restrict__ logs_q,
                                                const int* __restrict__ lens,
                                                const int* __restrict__ idx_map,
                                                float* __restrict__ out,
                                                float* __restrict__ partials) {
    const int S = BB * CC * TYY / 4;
    int base = blockIdx.x * 256 + threadIdx.x;
    float klsum = 0.f;
#pragma unroll
    for (int r = 0; r < 4; ++r) {
        int i = base + r * S;
        int t = i & (TYY - 1);
        int bc = i >> 11;
        int b = bc / CC;
        float ma = 0.f, la = 0.f;
        if (t < lens[8 + b]) {
            int x = idx_map[b * TYY + t];
            size_t off = (size_t)bc * TXX + x;
            ma = m_p[off];
            la = logs_p[off];
            float zv = z_p[i], lq = logs_q[i];
            float dz = zv - ma;
            klsum += la - lq - 0.5f + 0.5f * dz * dz * expf(-2.0f * la);
        }
        out[O1 + i] = ma;
        out[O2 + i] = la;
    }
    for (int o = 32; o > 0; o >>= 1) klsum += __shfl_down(klsum, o);
    __shared__ float red[4];
    if ((threadIdx.x & 63) == 0) red[threadIdx.x >> 6] = klsum;
    __syncthreads();
    if (threadIdx.x == 0) partials[blockIdx.x] = red[0] + red[1] + red[2] + red[3];
}

__global__ void k_final(const float* __restrict__ partials, const int* __restrict__ lens,
                        float* __restrict__ out) {
    float s = 0.f;
    for (int i = threadIdx.x; i < 3072; i += 256) s += partials[i];
    for (int o = 32; o > 0; o >>= 1) s += __shfl_down(s, o);
    __shared__ float red[4];
    if ((threadIdx.x & 63) == 0) red[threadIdx.x >> 6] = s;
    __syncthreads();
    if (threadIdx.x == 0) {
        float tot = 0.f;
        for (int b = 0; b < 8; ++b) tot += (float)lens[8 + b];
        out[O3] = (red[0] + red[1] + red[2] + red[3]) / tot;
    }
}

extern "C" void kernel_launch(void* const* d_in, const int* in_sizes, int n_in,
                              void* d_out, int out_size, void* d_ws, size_t ws_size,
                              hipStream_t stream) {
    const float* z_p    = (const float*)d_in[0];
    const float* m_p    = (const float*)d_in[1];
    const float* logs_p = (const float*)d_in[2];
    const float* logs_q = (const float*)d_in[3];
    const float* tmask  = (const float*)d_in[4];
    const float* smask  = (const float*)d_in[5];
    float* out = (float*)d_out;
    char* ws = (char*)d_ws;

    float*    neg      = (float*)(ws + WS_NEG);
    float*    sarr     = (float*)(ws + WS_S);
    float*    msr      = (float*)(ws + WS_MSR);
    float*    bias     = (float*)(ws + WS_BIAS);
    uint32_t* dirs     = (uint32_t*)(ws + WS_DIRS);
    int*      idx_map  = (int*)(ws + WS_IDX);
    int*      lens     = (int*)(ws + WS_LENS);
    float*    partials = (float*)(ws + WS_PART);

    hipLaunchKernelGGL(k_zero,    dim3(2048),      dim3(256), 0, stream, out);
    hipLaunchKernelGGL(k_prep,    dim3(3072),      dim3(256), 0, stream, logs_p, m_p, sarr, msr);
    hipLaunchKernelGGL(k_bias,    dim3(16),        dim3(256), 0, stream, logs_p, m_p, msr, bias);
    hipLaunchKernelGGL(k_len,     dim3(8),         dim3(256), 0, stream, tmask, smask, lens);
    hipLaunchKernelGGL(k_gemm,    dim3(8, 32, 8),  dim3(256), 0, stream, z_p, msr, sarr, bias, lens, neg);
    hipLaunchKernelGGL(k_fwd,     dim3(8),         dim3(64),  0, stream, neg, lens, dirs);
    hipLaunchKernelGGL(k_bwd,     dim3(8),         dim3(64),  0, stream, lens, dirs, idx_map);
    hipLaunchKernelGGL(k_scatter, dim3(64),        dim3(256), 0, stream, lens, idx_map, out);
    hipLaunchKernelGGL(k_gather,  dim3(3072),      dim3(256), 0, stream, z_p, m_p, logs_p, logs_q,
                       lens, idx_map, out, partials);
    hipLaunchKernelGGL(k_final,   dim3(1),         dim3(256), 0, stream, partials, lens, out);
}